// Round 5
// baseline (2100.062 us; speedup 1.0000x reference)
//
#include <hip/hip_runtime.h>

typedef __bf16 bf16x8 __attribute__((ext_vector_type(8)));
typedef float  f32x4  __attribute__((ext_vector_type(4)));

#define ND   64
#define HD   128
#define NSEG 1024
#define RPB  512
#define REPS 4          // diagnostic inner repeat: makes k_phi dispatches > harness fills

__device__ __forceinline__ int lower_bound_i(const int* __restrict__ a, int n, int v) {
  int lo = 0, hi = n;
  while (lo < hi) { int m = (lo + hi) >> 1; if (a[m] < v) lo = m + 1; else hi = m; }
  return lo;
}

__global__ __launch_bounds__(128) void k_init(const int* __restrict__ xb, int n,
                                              float* __restrict__ sums,
                                              float* __restrict__ counts) {
  const int s = blockIdx.x;
  sums[s * HD + threadIdx.x] = 0.f;
  if (threadIdx.x == 0) {
    int lo = lower_bound_i(xb, n, s);
    int hi = lower_bound_i(xb, n, s + 1);
    counts[s] = (float)(hi - lo);
  }
}

__device__ __forceinline__ void flush_seg(float* __restrict__ sums, int seg,
                                          float* seg_acc, int lane) {
  #pragma unroll
  for (int ct = 0; ct < 8; ++ct) {
    float v = seg_acc[ct];
    v += __shfl_xor(v, 16);
    v += __shfl_xor(v, 32);
    if (lane < 16) atomicAdd(&sums[seg * HD + ct * 16 + lane], v);
  }
}

// Shared phi body. LM=0: R2 fragment-layout loads (strided 16B chunks).
// LM=1: lane-contiguous loads (minimal L1 lines/instr) -> WRONG fragment data,
// used only as a load-throughput probe; its sums output is discarded+reinit.
template<int LM>
__device__ __forceinline__ void phi_body(const float* __restrict__ x,
                                         const int* __restrict__ xb,
                                         const float* __restrict__ W1,
                                         const float* __restrict__ b1,
                                         float* __restrict__ sums, int n) {
  __shared__ __align__(16) char ldsW[16 * 1024];
  const int lane = threadIdx.x & 63;
  const int wave = threadIdx.x >> 6;
  const int l16  = lane & 15;
  const int lgrp = lane >> 4;

  #pragma unroll
  for (int i = 0; i < 4; ++i) {
    const int f = wave + i * 4, kt = f >> 3, ct = f & 7;
    bf16x8 fr;
    #pragma unroll
    for (int e = 0; e < 8; ++e)
      fr[e] = (__bf16)W1[(kt * 32 + lgrp * 8 + e) * HD + ct * 16 + l16];
    *(bf16x8*)(&ldsW[f * 1024 + lane * 16]) = fr;
  }
  float b1v[8];
  #pragma unroll
  for (int ct = 0; ct < 8; ++ct) b1v[ct] = b1[ct * 16 + l16];
  __syncthreads();

  const int row0 = blockIdx.x * RPB;
  if (row0 >= n) return;
  const int iters = min(RPB, n - row0) >> 6;   // n % 64 == 0

  const float* xp = x + (size_t)(row0 + wave * 16 + l16) * ND + lgrp * 8;  // LM==0
  const char*  xc = (const char*)x + (size_t)(row0 + wave * 16) * 256;     // LM==1
  const int*   xbp = xb + row0 + wave * 16 + l16;

#define LOADT(T, R0, R1, R2, R3, SB)                                  \
  {                                                                   \
    if constexpr (LM == 0) {                                          \
      const float* _p = xp + (size_t)(T) * (64 * ND);                 \
      R0 = *(const f32x4*)(_p);      R1 = *(const f32x4*)(_p + 4);    \
      R2 = *(const f32x4*)(_p + 32); R3 = *(const f32x4*)(_p + 36);   \
    } else {                                                          \
      const char* _p = xc + (size_t)(T) * 16384 + lane * 16;          \
      R0 = *(const f32x4*)(_p);        R1 = *(const f32x4*)(_p + 1024);\
      R2 = *(const f32x4*)(_p + 2048); R3 = *(const f32x4*)(_p + 3072);\
    }                                                                 \
    SB = xbp[(T) * 64];                                               \
  }

  for (int rep = 0; rep < REPS; ++rep) {
    float seg_acc[8] = {0.f, 0.f, 0.f, 0.f, 0.f, 0.f, 0.f, 0.f};
    int   seg_cur = -1;
    f32x4 v0, v1, v2, v3; int sb;
    f32x4 w0, w1, w2, w3; int sbn;

    LOADT(0, v0, v1, v2, v3, sb);

    for (int t = 0; t < iters; ++t) {
      const int tn = (t + 1 < iters) ? (t + 1) : t;
      LOADT(tn, w0, w1, w2, w3, sbn);

      {
        int sfirst = __builtin_amdgcn_readfirstlane(sb);
        const bool uni = (__all(sb == sfirst) != 0);
        bf16x8 a0, a1;
        #pragma unroll
        for (int e = 0; e < 4; ++e) {
          a0[e] = (__bf16)v0[e]; a0[e + 4] = (__bf16)v1[e];
          a1[e] = (__bf16)v2[e]; a1[e + 4] = (__bf16)v3[e];
        }
        int lb = lane * 16;
        asm volatile("" : "+v"(lb));   // defeat LICM on the LDS frag reads
        f32x4 acc[8];
        #pragma unroll
        for (int ct = 0; ct < 8; ++ct) {
          f32x4 c; c[0] = c[1] = c[2] = c[3] = b1v[ct];
          bf16x8 f0 = *(const bf16x8*)(&ldsW[ct * 1024 + lb]);
          bf16x8 f1 = *(const bf16x8*)(&ldsW[(8 + ct) * 1024 + lb]);
          c = __builtin_amdgcn_mfma_f32_16x16x32_bf16(a0, f0, c, 0, 0, 0);
          c = __builtin_amdgcn_mfma_f32_16x16x32_bf16(a1, f1, c, 0, 0, 0);
          acc[ct] = c;
        }
        if (uni) {
          if (sfirst != seg_cur) {
            if (seg_cur >= 0) flush_seg(sums, seg_cur, seg_acc, lane);
            #pragma unroll
            for (int ct = 0; ct < 8; ++ct) seg_acc[ct] = 0.f;
            seg_cur = sfirst;
          }
          #pragma unroll
          for (int ct = 0; ct < 8; ++ct)
            seg_acc[ct] += (fmaxf(acc[ct][0], 0.f) + fmaxf(acc[ct][1], 0.f)) +
                           (fmaxf(acc[ct][2], 0.f) + fmaxf(acc[ct][3], 0.f));
        } else {
          if (seg_cur >= 0) flush_seg(sums, seg_cur, seg_acc, lane);
          #pragma unroll
          for (int ct = 0; ct < 8; ++ct) seg_acc[ct] = 0.f;
          const int* xq = xb + row0 + t * 64 + wave * 16 + lgrp * 4;
          const int s0 = xq[0], s1 = xq[1], s2 = xq[2], s3 = xq[3];
          #pragma unroll
          for (int ct = 0; ct < 8; ++ct) {
            atomicAdd(&sums[s0 * HD + ct * 16 + l16], fmaxf(acc[ct][0], 0.f));
            atomicAdd(&sums[s1 * HD + ct * 16 + l16], fmaxf(acc[ct][1], 0.f));
            atomicAdd(&sums[s2 * HD + ct * 16 + l16], fmaxf(acc[ct][2], 0.f));
            atomicAdd(&sums[s3 * HD + ct * 16 + l16], fmaxf(acc[ct][3], 0.f));
          }
          seg_cur = __shfl(sb, 15);
        }
      }

      v0 = w0; v1 = w1; v2 = w2; v3 = w3; sb = sbn;
    }
    if (seg_cur >= 0) flush_seg(sums, seg_cur, seg_acc, lane);
  }
#undef LOADT
}

// v1: R2-best structure (reference counters + final real pass)
__global__ __launch_bounds__(256, 4) void k_phi_v1(const float* __restrict__ x,
                                                   const int* __restrict__ xb,
                                                   const float* __restrict__ W1,
                                                   const float* __restrict__ b1,
                                                   float* __restrict__ sums, int n) {
  phi_body<0>(x, xb, W1, b1, sums, n);
}
// v2: occupancy probe (6 waves/EU requested)
__global__ __launch_bounds__(256, 6) void k_phi_v2(const float* __restrict__ x,
                                                   const int* __restrict__ xb,
                                                   const float* __restrict__ W1,
                                                   const float* __restrict__ b1,
                                                   float* __restrict__ sums, int n) {
  phi_body<0>(x, xb, W1, b1, sums, n);
}
// v3: L1-transaction probe (contiguous loads, garbage math, output discarded)
__global__ __launch_bounds__(256, 4) void k_phi_v3(const float* __restrict__ x,
                                                   const int* __restrict__ xb,
                                                   const float* __restrict__ W1,
                                                   const float* __restrict__ b1,
                                                   float* __restrict__ sums, int n) {
  phi_body<1>(x, xb, W1, b1, sums, n);
}

__global__ __launch_bounds__(128) void k_rho(const float* __restrict__ sums,
                                             const float* __restrict__ counts,
                                             const float* __restrict__ W2, const float* __restrict__ b2,
                                             const float* __restrict__ W3, const float* __restrict__ b3,
                                             const float* __restrict__ W4, const float* __restrict__ b4,
                                             float* __restrict__ out) {
  const int s = blockIdx.x;
  const int j = threadIdx.x;
  __shared__ float bufA[HD];
  __shared__ float bufB[HD];

  const float c = counts[s];
  const float inv = 1.f / ((float)REPS * fmaxf(c, 1.f));   // sums holds REPS x the true sum
  bufA[j] = sums[s * HD + j] * inv;
  __syncthreads();

  float hid = b2[j];
  #pragma unroll 4
  for (int k = 0; k < HD; ++k) hid = fmaf(bufA[k], W2[k * HD + j], hid);
  if (c == 0.f) hid = 0.f;
  bufB[j] = hid;
  __syncthreads();

  float t = b3[j];
  #pragma unroll 4
  for (int k = 0; k < HD; ++k) t = fmaf(bufB[k], W3[k * HD + j], t);
  t = fmaxf(t, 0.f);
  bufA[j] = t;
  __syncthreads();

  if (j < 16) {
    float o = b4[j];
    #pragma unroll 4
    for (int k = 0; k < HD; ++k) o = fmaf(bufA[k], W4[k * 16 + j], o);
    out[s * 16 + j] = o;
  }
}

extern "C" void kernel_launch(void* const* d_in, const int* in_sizes, int n_in,
                              void* d_out, int out_size, void* d_ws, size_t ws_size,
                              hipStream_t stream) {
  const float* x  = (const float*)d_in[0];
  const int*   xb = (const int*)  d_in[1];
  const float* W1 = (const float*)d_in[2];
  const float* b1 = (const float*)d_in[3];
  const float* W2 = (const float*)d_in[4];
  const float* b2 = (const float*)d_in[5];
  const float* W3 = (const float*)d_in[6];
  const float* b3 = (const float*)d_in[7];
  const float* W4 = (const float*)d_in[8];
  const float* b4 = (const float*)d_in[9];
  float* out = (float*)d_out;
  const int n = in_sizes[1];

  float* sums   = (float*)d_ws;              // [NSEG][HD]
  float* counts = sums + (size_t)NSEG * HD;  // [NSEG]

  const int nb = (n + RPB - 1) / RPB;

  // diagnostic sequence: each variant's dispatch is ~4x k_phi so it surfaces
  // in rocprof top-5 with its own counters; sums re-zeroed between variants.
  k_init<<<NSEG, 128, 0, stream>>>(xb, n, sums, counts);
  k_phi_v1<<<nb, 256, 0, stream>>>(x, xb, W1, b1, sums, n);
  k_init<<<NSEG, 128, 0, stream>>>(xb, n, sums, counts);
  k_phi_v2<<<nb, 256, 0, stream>>>(x, xb, W1, b1, sums, n);
  k_init<<<NSEG, 128, 0, stream>>>(xb, n, sums, counts);
  k_phi_v3<<<nb, 256, 0, stream>>>(x, xb, W1, b1, sums, n);   // garbage probe
  k_init<<<NSEG, 128, 0, stream>>>(xb, n, sums, counts);
  k_phi_v1<<<nb, 256, 0, stream>>>(x, xb, W1, b1, sums, n);   // real pass
  k_rho<<<NSEG, 128, 0, stream>>>(sums, counts, W2, b2, W3, b3, W4, b4, out);
}

// Round 6
// 142.666 us; speedup vs baseline: 14.7201x; 14.7201x over previous
//
#include <hip/hip_runtime.h>

typedef __bf16 bf16x8 __attribute__((ext_vector_type(8)));
typedef float  f32x4  __attribute__((ext_vector_type(4)));

#define ND   64
#define HD   128
#define NSEG 1024

__device__ __forceinline__ int lower_bound_i(const int* __restrict__ a, int n, int v) {
  int lo = 0, hi = n;
  while (lo < hi) { int m = (lo + hi) >> 1; if (a[m] < v) lo = m + 1; else hi = m; }
  return lo;
}

// K0: seg_start[s] = first row of segment s (xb sorted); seg_start[NSEG] = n.
__global__ __launch_bounds__(128) void k_bounds(const int* __restrict__ xb, int n,
                                                int* __restrict__ ss) {
  const int s = blockIdx.x * 128 + threadIdx.x;
  if (s <= NSEG) ss[s] = lower_bound_i(xb, n, s);
}

// K1: one block per segment; 4 waves; wave w owns tiles w, w+4, w+8, ... of the
// segment's contiguous rows. NO atomics, NO xb loads, NO branches in the hot
// loop. seg sum -> LDS reduce -> single plain store. W1 frags in LDS (R2-best).
// A frag: lane=(l16 row, lgrp kgrp), k = kt*32 + lgrp*8 + e. B frag: same k map.
// D frag: col = lane&15, row = 4*(lane>>4)+reg  (HW-verified R1-R5).
__global__ __launch_bounds__(256, 4) void k_phi(const float* __restrict__ x,
                                                const int* __restrict__ ss,
                                                const float* __restrict__ W1,
                                                const float* __restrict__ b1,
                                                float* __restrict__ sums) {
  __shared__ __align__(16) char ldsW[16 * 1024];
  __shared__ float ldsR[4 * HD];
  const int lane = threadIdx.x & 63;
  const int wave = threadIdx.x >> 6;
  const int l16  = lane & 15;
  const int lgrp = lane >> 4;
  const int s    = blockIdx.x;

  const int r0   = ss[s];
  const int rows = ss[s + 1] - r0;

  // stage W1 fragments into LDS: frag f = kt*8+ct at [f][lane][16B]
  #pragma unroll
  for (int i = 0; i < 4; ++i) {
    const int f = wave + i * 4, kt = f >> 3, ct = f & 7;
    bf16x8 fr;
    #pragma unroll
    for (int e = 0; e < 8; ++e)
      fr[e] = (__bf16)W1[(kt * 32 + lgrp * 8 + e) * HD + ct * 16 + l16];
    *(bf16x8*)(&ldsW[f * 1024 + lane * 16]) = fr;
  }
  float b1v[8];
  #pragma unroll
  for (int ct = 0; ct < 8; ++ct) b1v[ct] = b1[ct * 16 + l16];
  __syncthreads();

  float seg_acc[8] = {0.f, 0.f, 0.f, 0.f, 0.f, 0.f, 0.f, 0.f};
  const int tiles = (rows + 15) >> 4;

#define LOADT(T, R0, R1, R2, R3)                                   \
  {                                                                \
    const int rr = min((T) * 16 + l16, rows - 1);                  \
    const float* _p = x + (size_t)(r0 + rr) * ND + lgrp * 8;       \
    R0 = *(const f32x4*)(_p);      R1 = *(const f32x4*)(_p + 4);   \
    R2 = *(const f32x4*)(_p + 32); R3 = *(const f32x4*)(_p + 36);  \
  }

  int t = wave;
  if (t < tiles) {
    f32x4 v0, v1, v2, v3;
    LOADT(t, v0, v1, v2, v3);
    for (;;) {
      const int tn = t + 4;
      const int tp = min(tn, tiles - 1);
      f32x4 w0, w1, w2, w3;
      LOADT(tp, w0, w1, w2, w3);      // depth-1 prefetch (dup-load at tail, harmless)

      bf16x8 a0, a1;
      #pragma unroll
      for (int e = 0; e < 4; ++e) {
        a0[e] = (__bf16)v0[e]; a0[e + 4] = (__bf16)v1[e];
        a1[e] = (__bf16)v2[e]; a1[e + 4] = (__bf16)v3[e];
      }
      int lb = lane * 16;
      asm volatile("" : "+v"(lb));    // defeat LICM: keep frag reads in-loop
      f32x4 acc[8];
      #pragma unroll
      for (int ct = 0; ct < 8; ++ct) {
        f32x4 c; c[0] = c[1] = c[2] = c[3] = b1v[ct];
        bf16x8 f0 = *(const bf16x8*)(&ldsW[ct * 1024 + lb]);
        bf16x8 f1 = *(const bf16x8*)(&ldsW[(8 + ct) * 1024 + lb]);
        c = __builtin_amdgcn_mfma_f32_16x16x32_bf16(a0, f0, c, 0, 0, 0);
        c = __builtin_amdgcn_mfma_f32_16x16x32_bf16(a1, f1, c, 0, 0, 0);
        acc[ct] = c;
      }

      const int lim = rows - t * 16;     // >=16 for all but the last tile
      if (lim >= 16) {
        #pragma unroll
        for (int ct = 0; ct < 8; ++ct)
          seg_acc[ct] += (fmaxf(acc[ct][0], 0.f) + fmaxf(acc[ct][1], 0.f)) +
                         (fmaxf(acc[ct][2], 0.f) + fmaxf(acc[ct][3], 0.f));
      } else {
        #pragma unroll
        for (int ct = 0; ct < 8; ++ct)
          #pragma unroll
          for (int i = 0; i < 4; ++i)
            seg_acc[ct] += (4 * lgrp + i < lim) ? fmaxf(acc[ct][i], 0.f) : 0.f;
      }

      v0 = w0; v1 = w1; v2 = w2; v3 = w3;
      t = tn;
      if (t >= tiles) break;
    }
  }
#undef LOADT

  // cross-rowgroup then cross-wave reduce; single plain store (no atomics)
  #pragma unroll
  for (int ct = 0; ct < 8; ++ct) {
    float v = seg_acc[ct];
    v += __shfl_xor(v, 16);
    v += __shfl_xor(v, 32);
    if (lane < 16) ldsR[wave * HD + ct * 16 + l16] = v;
  }
  __syncthreads();
  if (threadIdx.x < HD) {
    const float r = ldsR[threadIdx.x] + ldsR[HD + threadIdx.x] +
                    ldsR[2 * HD + threadIdx.x] + ldsR[3 * HD + threadIdx.x];
    sums[s * HD + threadIdx.x] = r;
  }
}

// K2: per segment: mean -> @W2+b2 (deferred past the mean) -> relu(@W3+b3) -> @W4+b4
__global__ __launch_bounds__(128) void k_rho(const float* __restrict__ sums,
                                             const int* __restrict__ ss,
                                             const float* __restrict__ W2, const float* __restrict__ b2,
                                             const float* __restrict__ W3, const float* __restrict__ b3,
                                             const float* __restrict__ W4, const float* __restrict__ b4,
                                             float* __restrict__ out) {
  const int s = blockIdx.x;
  const int j = threadIdx.x;
  __shared__ float bufA[HD];
  __shared__ float bufB[HD];

  const float c = (float)(ss[s + 1] - ss[s]);
  const float inv = 1.f / fmaxf(c, 1.f);
  bufA[j] = sums[s * HD + j] * inv;
  __syncthreads();

  float hid = b2[j];
  #pragma unroll 4
  for (int k = 0; k < HD; ++k) hid = fmaf(bufA[k], W2[k * HD + j], hid);
  if (c == 0.f) hid = 0.f;                    // reference: empty segment -> hid = 0
  bufB[j] = hid;
  __syncthreads();

  float t = b3[j];
  #pragma unroll 4
  for (int k = 0; k < HD; ++k) t = fmaf(bufB[k], W3[k * HD + j], t);
  t = fmaxf(t, 0.f);
  bufA[j] = t;
  __syncthreads();

  if (j < 16) {
    float o = b4[j];
    #pragma unroll 4
    for (int k = 0; k < HD; ++k) o = fmaf(bufA[k], W4[k * 16 + j], o);
    out[s * 16 + j] = o;
  }
}

extern "C" void kernel_launch(void* const* d_in, const int* in_sizes, int n_in,
                              void* d_out, int out_size, void* d_ws, size_t ws_size,
                              hipStream_t stream) {
  const float* x  = (const float*)d_in[0];
  const int*   xb = (const int*)  d_in[1];
  const float* W1 = (const float*)d_in[2];
  const float* b1 = (const float*)d_in[3];
  const float* W2 = (const float*)d_in[4];
  const float* b2 = (const float*)d_in[5];
  const float* W3 = (const float*)d_in[6];
  const float* b3 = (const float*)d_in[7];
  const float* W4 = (const float*)d_in[8];
  const float* b4 = (const float*)d_in[9];
  float* out = (float*)d_out;
  const int n = in_sizes[1];

  float* sums = (float*)d_ws;                      // [NSEG][HD]
  int*   ss   = (int*)(sums + (size_t)NSEG * HD);  // [NSEG+1]

  k_bounds<<<(NSEG + 1 + 127) / 128, 128, 0, stream>>>(xb, n, ss);
  k_phi<<<NSEG, 256, 0, stream>>>(x, ss, W1, b1, sums);
  k_rho<<<NSEG, 128, 0, stream>>>(sums, ss, W2, b2, W3, b3, W4, b4, out);
}